// Round 8
// baseline (6448.932 us; speedup 1.0000x reference)
//
#include <hip/hip_runtime.h>
#include <hip/hip_bf16.h>
#include <hip/hip_fp16.h>

#define T_DIM 8192
#define H_DIM 3200
#define I_DIM 12800

typedef int v4i __attribute__((ext_vector_type(4)));
typedef _Float16 h8 __attribute__((ext_vector_type(8)));

__device__ __forceinline__ void gload16(const void* g, void* l) {
    __builtin_amdgcn_global_load_lds(
        (const __attribute__((address_space(1))) unsigned int*)g,
        (__attribute__((address_space(3))) unsigned int*)l, 16, 0, 0);
}

// ---------------- int32 -> int8 repack (memory-bound) ----------------
__global__ __launch_bounds__(256) void repack_kernel(const int* __restrict__ src,
                                                     unsigned int* __restrict__ dst,
                                                     long n4) {
    long i = (long)blockIdx.x * blockDim.x + threadIdx.x;
    long stride = (long)gridDim.x * blockDim.x;
    for (; i < n4; i += stride) {
        int4 v = ((const int4*)src)[i];
        dst[i] = (unsigned int)((v.x & 255) | ((v.y & 255) << 8) |
                                ((v.z & 255) << 16) | ((v.w & 255) << 24));
    }
}

// ---------------- i8 GEMM, C[M][N] = A[M][K] * B[N][K]^T ----------------
// R7 structure (best: 400 us/GEMM, MfmaUtil 38%) with LDS ring 4 -> 2
// (64 KiB/block) => 2 BLOCKS/CU (16 waves, 4/SIMD). R7's phase arithmetic:
// phase = LDS(700cy) + MFMA(653cy) SERIAL because the end-of-phase barrier
// aligns the CU's only block's waves; a 2nd co-resident block fills each
// pipe's idle half (m114 co-schedule mechanism). Tile stays 256x256 (R5
// showed 128-tile halves intensity and explodes FETCH 250->570 MB).
// 512 threads = 8 waves (2M x 4N), per-wave 128x64, mfma_i32_16x16x64_i8.
// 4 phases per 128-B K-tile (halves g, g+1), ring-of-2 slots per operand:
//   ph0: read A0-3,B0-3 of half g (slot 0); STAGE A(g+1)+B(g+1) -> slot 1
//        [slot 1 freed: half g-1's reads done before prev-ph3 barrier]
//   ph1: read A4-7 (B reuse); gate vmcnt(0)  [g+1's 4 loads: ~1 phase flight]
//   ph2: read half g+1 (slot 1); STAGE A(g+2)+B(g+2) -> slot 0
//        [slot 0 freed: half g's reads done before ph1 barrier]
//   ph3: read A4-7 of g+1; gate vmcnt(0)
// Each phase: { ds_read frags ; stage ; setprio1 ; 16 MFMA ; setprio0 ;
// [gate] ; ONE s_barrier } (single-barrier phase: R4/R7 evidence, +9%+4%).
// Staged units get >= 1 phase (~1500 cyc > 900-cyc HBM latency) before their
// gate, so the vmcnt(0) drain is mostly retired; the other block covers the
// rest. Write-after-read safety: skew <= 1 phase; every slot is re-staged
// only after the barrier that its last readers crossed with reads complete.
// LDS dest of global_load_lds is LINEAR; XOR swizzle (16B chunk
// cc ^= (row>>1)&3) pre-applied to per-lane GLOBAL source and ds_read addrs
// (0-conflict, measured). strideA/strideB in BYTES. EPI=0: fp16 out;
// EPI=1: fp32 of fp16-rounded. fc2's N=3200 runs on 13 col-guarded tiles.
// No XCD swizzle (L3-resident regime).
template <int EPI>
__global__ __launch_bounds__(512, 4) void gemm_i8_2b(
    const signed char* __restrict__ A, long strideA,
    const signed char* __restrict__ B, long strideB,
    int Ntrue, int K, int ldc,
    const float* __restrict__ rowscale, const float* __restrict__ colscale,
    const float* __restrict__ bias, void* __restrict__ Cout) {
    __shared__ signed char lds[65536];
    signed char* ldsA = lds;           // 2 slots x 16384 B (256 rows x 64 B)
    signed char* ldsB = lds + 32768;   // 2 slots x 16384 B

    const int tid = threadIdx.x;
    const int lane = tid & 63, wid = tid >> 6;
    const int wr = wid >> 2, wc = wid & 3;
    const int bm = blockIdx.x, bn = blockIdx.y;
    const long Arow0 = (long)bm * 256;
    const long Bcol0 = (long)bn * 256;

    // Staging: unit = 256 rows x 64 B = 1024 chunks of 16 B; thread handles
    // chunks c0 = tid and c1 = tid+512. LDS dest is linear (uniform base +
    // lane*16); the swizzle is folded into the per-lane GLOBAL source chunk.
    const int c0 = tid, c1 = tid + 512;
    const int r0 = c0 >> 2, r1 = c1 >> 2;
    const int s0 = (((c0 & 3) ^ ((r0 >> 1) & 3)) << 4);
    const int s1 = (((c1 & 3) ^ ((r1 >> 1) & 3)) << 4);
    const signed char* Ag0 = A + (Arow0 + r0) * strideA + s0;
    const signed char* Ag1 = A + (Arow0 + r1) * strideA + s1;
    const signed char* Bg0 = B + (Bcol0 + r0) * strideB + s0;
    const signed char* Bg1 = B + (Bcol0 + r1) * strideB + s1;
    const int d0 = c0 * 16, d1 = c1 * 16;

    const int NH = K >> 6;   // number of 64-byte K-halves
    const int nkt = K >> 7;  // loop bodies (1 K-tile = 2 halves = 4 phases)

#define STAGE_A(h)                                  \
    {                                               \
        const int hc_ = (h) < NH ? (h) : NH - 1;    \
        const long ko_ = (long)hc_ << 6;            \
        signed char* d_ = ldsA + (((h) & 1) << 14); \
        gload16(Ag0 + ko_, d_ + d0);                \
        gload16(Ag1 + ko_, d_ + d1);                \
    }
#define STAGE_B(h)                                  \
    {                                               \
        const int hc_ = (h) < NH ? (h) : NH - 1;    \
        const long ko_ = (long)hc_ << 6;            \
        signed char* d_ = ldsB + (((h) & 1) << 14); \
        gload16(Bg0 + ko_, d_ + d0);                \
        gload16(Bg1 + ko_, d_ + d1);                \
    }

    // Fragment read offsets: lane reads 16 B at (row, k-chunk q) -> LDS chunk
    // q ^ ((row>>1)&3); per-lane constant swz. Frag i lives at +i*1024.
    const int r = lane & 15, q = lane >> 4;
    const int swz = ((q ^ ((r >> 1) & 3)) << 4);
    const int aoff = (wr * 128 + r) * 64 + swz;  // + i*1024, i = 0..7
    const int boff = (wc * 64 + r) * 64 + swz;   // + n*1024, n = 0..3

    v4i acc[8][4] = {};
    v4i af[4], bf[4];

    // Phase: read frags -> stage -> setprio(1) -> 16 MFMA -> setprio(0) ->
    // [gate] -> ONE barrier. Compiler inserts per-consumer lgkm waits.
#define PHASE(SLOTA, SLOTB, AIDX, LOADB, ACCOFF, STAGE_STMT, GATE_STMT)     \
    {                                                                       \
        _Pragma("unroll") for (int i = 0; i < 4; ++i)                       \
            af[i] = *(const v4i*)((SLOTA) + aoff + ((AIDX) + i) * 1024);    \
        if (LOADB) {                                                        \
            _Pragma("unroll") for (int n = 0; n < 4; ++n)                   \
                bf[n] = *(const v4i*)((SLOTB) + boff + n * 1024);           \
        }                                                                   \
        STAGE_STMT;                                                         \
        __builtin_amdgcn_s_setprio(1);                                      \
        _Pragma("unroll") for (int m = 0; m < 4; ++m)                       \
            _Pragma("unroll") for (int n = 0; n < 4; ++n)                   \
                acc[m + (ACCOFF)][n] = __builtin_amdgcn_mfma_i32_16x16x64_i8( \
                    af[m], bf[n], acc[m + (ACCOFF)][n], 0, 0, 0);           \
        __builtin_amdgcn_s_setprio(0);                                      \
        GATE_STMT;                                                          \
        __builtin_amdgcn_s_barrier();                                       \
    }

    // Prologue: stage half 0 only; drain; half 1 is staged at ph0 of kt=0.
    STAGE_A(0); STAGE_B(0);
    asm volatile("s_waitcnt vmcnt(0)");
    __builtin_amdgcn_s_barrier();

    const signed char* sA0 = ldsA;
    const signed char* sB0 = ldsB;
    const signed char* sA1 = ldsA + 16384;
    const signed char* sB1 = ldsB + 16384;
    for (int kt = 0; kt < nkt; ++kt) {
        const int g = kt << 1;  // even half in slot 0, odd in slot 1
        // ph0: half g, A0-3 x B0-3 ; stage half g+1 -> slot 1
        PHASE(sA0, sB0, 0, true, 0, { STAGE_A(g + 1); STAGE_B(g + 1); }, );
        // ph1: half g, A4-7 x B0-3 ; gate: half g+1 resident (~1 phase flight)
        PHASE(sA0, sB0, 4, false, 4, , asm volatile("s_waitcnt vmcnt(0)"));
        // ph2: half g+1, A0-3 x B0-3 ; stage half g+2 -> slot 0
        PHASE(sA1, sB1, 0, true, 0, { STAGE_A(g + 2); STAGE_B(g + 2); }, );
        // ph3: half g+1, A4-7 x B0-3 ; gate: half g+2 resident
        PHASE(sA1, sB1, 4, false, 4, , asm volatile("s_waitcnt vmcnt(0)"));
    }

    // Epilogue: C/D layout col = lane&15, row = (lane>>4)*4 + reg.
    const int row0 = bm * 256 + wr * 128;
    const int col0 = bn * 256 + wc * 64;
    const int r4 = (lane >> 4) << 2, cl = lane & 15;
#pragma unroll
    for (int m = 0; m < 8; ++m) {
        const int rowb = row0 + m * 16 + r4;
        float rs[4];
#pragma unroll
        for (int rr = 0; rr < 4; ++rr) rs[rr] = rowscale[rowb + rr];
#pragma unroll
        for (int n = 0; n < 4; ++n) {
            const int col = col0 + n * 16 + cl;
            if (col < Ntrue) {
                const float cs = colscale[col];
                const float bs = bias[col];
#pragma unroll
                for (int rr = 0; rr < 4; ++rr) {
                    float v = (float)acc[m][n][rr];
                    v = __fmul_rn(v, rs[rr]);
                    v = __fmul_rn(v, cs);
                    v = __fadd_rn(v, bs);
                    _Float16 hh = (_Float16)v;  // reference rounds to fp16
                    const size_t idx = (size_t)(rowb + rr) * ldc + col;
                    if (EPI == 0) ((_Float16*)Cout)[idx] = hh;
                    else ((float*)Cout)[idx] = (float)hh;
                }
            }
        }
    }
#undef PHASE
#undef STAGE_A
#undef STAGE_B
}

// -------- exact GELU + per-token dynamic int8 requant (in-place act_q) -------
__global__ __launch_bounds__(256) void gelu_quant(_Float16* __restrict__ fc1,
                                                  float* __restrict__ nscale) {
    __shared__ float gbuf[I_DIM];
    __shared__ float wmax[4];
    const int tid = threadIdx.x, lane = tid & 63, wid = tid >> 6;
    const long t = blockIdx.x;
    const h8* row = (const h8*)(fc1 + t * I_DIM);
    float lmax = 0.f;
    for (int c = tid; c < I_DIM / 8; c += 256) {
        h8 v = row[c];
#pragma unroll
        for (int j = 0; j < 8; ++j) {
            float x = (float)v[j];
            float e = erff(__fdiv_rn(x, 1.41421356237309504880f));
            float g = __fmul_rn(__fmul_rn(0.5f, x), __fadd_rn(1.0f, e));
            gbuf[c * 8 + j] = g;
            lmax = fmaxf(lmax, fabsf(g));
        }
    }
#pragma unroll
    for (int off = 32; off; off >>= 1) lmax = fmaxf(lmax, __shfl_xor(lmax, off, 64));
    if (lane == 0) wmax[wid] = lmax;
    __syncthreads();
    const float gmax = fmaxf(fmaxf(wmax[0], wmax[1]), fmaxf(wmax[2], wmax[3]));
    const float ns = gmax / 127.0f;
    if (tid == 0) nscale[t] = ns;
    unsigned long long* out = (unsigned long long*)(fc1 + t * I_DIM);  // in-place
    for (int c = tid; c < I_DIM / 8; c += 256) {
        unsigned long long pk = 0;
#pragma unroll
        for (int j = 0; j < 8; ++j) {
            float qv = rintf(__fdiv_rn(gbuf[c * 8 + j], ns));
            qv = fminf(fmaxf(qv, -127.f), 127.f);
            pk |= ((unsigned long long)(unsigned char)(signed char)(int)qv) << (8 * j);
        }
        out[c] = pk;
    }
}

extern "C" void kernel_launch(void* const* d_in, const int* in_sizes, int n_in,
                              void* d_out, int out_size, void* d_ws, size_t ws_size,
                              hipStream_t stream) {
    const int* hs = (const int*)d_in[0];        // [B,S,H] int8-in-int32
    const float* scale = (const float*)d_in[1]; // [T]
    const int* w1 = (const int*)d_in[2];        // [I,H]
    const float* w1s = (const float*)d_in[3];   // [I]
    const float* b1 = (const float*)d_in[4];    // [I]
    const int* w2 = (const int*)d_in[5];        // [H,I]
    const float* w2s = (const float*)d_in[6];   // [H]
    const float* b2 = (const float*)d_in[7];    // [H]

    char* ws = (char*)d_ws;
    signed char* xq = (signed char*)ws;                     // 26,214,400 B
    signed char* w1q = xq + (size_t)T_DIM * H_DIM;          // 40,960,000 B
    signed char* w2q = w1q + (size_t)I_DIM * H_DIM;         // 40,960,000 B
    _Float16* fc1h = (_Float16*)(w2q + (size_t)H_DIM * I_DIM);  // chunkT*I fp16
    const size_t fixed = (size_t)T_DIM * H_DIM + 2 * (size_t)I_DIM * H_DIM;

    // choose smallest chunk count whose workspace fits ws_size (deterministic)
    int nc = 1;
    while (nc < 16) {
        size_t need = fixed + ((size_t)T_DIM / nc) * I_DIM * 2 +
                      ((size_t)T_DIM / nc) * 4 + 256;
        if (need <= ws_size) break;
        nc <<= 1;
    }
    const int chunkT = T_DIM / nc;
    float* nscale = (float*)((char*)fc1h + (size_t)chunkT * I_DIM * 2);

    repack_kernel<<<2048, 256, 0, stream>>>(hs, (unsigned int*)xq, (long)T_DIM * H_DIM / 4);
    repack_kernel<<<2048, 256, 0, stream>>>(w1, (unsigned int*)w1q, (long)I_DIM * H_DIM / 4);
    repack_kernel<<<2048, 256, 0, stream>>>(w2, (unsigned int*)w2q, (long)H_DIM * I_DIM / 4);

    const int n2tiles = (H_DIM + 255) / 256;  // 13; last tile col-guarded
    for (int c = 0; c < nc; ++c) {
        const int t0 = c * chunkT;
        gemm_i8_2b<0><<<dim3(chunkT / 256, I_DIM / 256), 512, 0, stream>>>(
            xq + (size_t)t0 * H_DIM, (long)H_DIM, w1q, (long)H_DIM,
            I_DIM, H_DIM, I_DIM,
            scale + t0, w1s, b1, (void*)fc1h);
        gelu_quant<<<chunkT, 256, 0, stream>>>(fc1h, nscale);
        gemm_i8_2b<1><<<dim3(chunkT / 256, n2tiles), 512, 0, stream>>>(
            (const signed char*)fc1h, (long)I_DIM * 2, w2q, (long)I_DIM,
            H_DIM, I_DIM, H_DIM,
            nscale, w2s, b2,
            (void*)((float*)d_out + (size_t)t0 * H_DIM));
    }
}

// Round 9
// 948.071 us; speedup vs baseline: 6.8022x; 6.8022x over previous
//
#include <hip/hip_runtime.h>
#include <hip/hip_bf16.h>
#include <hip/hip_fp16.h>

#define T_DIM 8192
#define H_DIM 3200
#define I_DIM 12800

typedef int v4i __attribute__((ext_vector_type(4)));
typedef _Float16 h8 __attribute__((ext_vector_type(8)));

__device__ __forceinline__ void gload16(const void* g, void* l) {
    __builtin_amdgcn_global_load_lds(
        (const __attribute__((address_space(1))) unsigned int*)g,
        (__attribute__((address_space(3))) unsigned int*)l, 16, 0, 0);
}

// ---------------- int32 -> int8 repack (memory-bound) ----------------
__global__ __launch_bounds__(256) void repack_kernel(const int* __restrict__ src,
                                                     unsigned int* __restrict__ dst,
                                                     long n4) {
    long i = (long)blockIdx.x * blockDim.x + threadIdx.x;
    long stride = (long)gridDim.x * blockDim.x;
    for (; i < n4; i += stride) {
        int4 v = ((const int4*)src)[i];
        dst[i] = (unsigned int)((v.x & 255) | ((v.y & 255) << 8) |
                                ((v.z & 255) << 16) | ((v.w & 255) << 24));
    }
}

// ---------------- i8 GEMM, C[M][N] = A[M][K] * B[N][K]^T ----------------
// Occupancy experiment, done right this time: 256x256 tile, 1024 threads =
// 16 waves (4M x 4N), per-wave 64x64 via mfma_i32_16x16x64_i8 -> acc[4][4]
// = 64 VGPR, total ~115 <= the 128-VGPR cap of 4 waves/SIMD (R8 spilled
// because 8-wave/128x64 needed ~180 under the same cap: VGPR=64 + 8.8 GB
// scratch writes). 4 waves/SIMD gives the CU skewed waves so ds_read bursts
// of some waves overlap MFMA clusters of others within the single-barrier
// phase (R7 at 2 waves/SIMD measured phase = LDS + MFMA serial, 38%).
// One phase per 64-byte K-half h:
//   { 8 ds_read_b128 (af[4], bf[4]) ; STAGE A(h+3)+B(h+3) (2 gload16/thread)
//     ; setprio1 ; 16 MFMA ; setprio0 ; vmcnt(4) ; ONE s_barrier }
// Ring-of-4 LDS slots/operand (128 KiB). Ledger (2 loads per A+B unit-pair):
// prologue stages halves 0,1,2 (6 in flight), gate vmcnt(4) -> half 0
// resident. Phase h stages h+3 (in flight h+1,h+2,h+3 = 6), gate retires
// h+1 -> entering h+1: resident h+1, in flight 4. Never drained to 0.
// Slot safety (skew <= 1 phase): STAGE(h+3) writes slot (h-1)&3 after the
// stager crossed barrier h-1; all readers of half h-1 completed their
// ds_reads before crossing that same barrier (MFMAs consumed them).
// LDS dest of global_load_lds is LINEAR; XOR swizzle (16B chunk
// cc ^= (row>>1)&3) pre-applied to per-lane GLOBAL source and ds_read addrs
// (0-conflict, measured). strideA/strideB in BYTES. EPI=0: fp16 out;
// EPI=1: fp32 of fp16-rounded. fc2's N=3200 runs on 13 col-guarded tiles.
// No XCD swizzle (L3-resident regime).
template <int EPI>
__global__ __launch_bounds__(1024, 4) void gemm_i8_16w(
    const signed char* __restrict__ A, long strideA,
    const signed char* __restrict__ B, long strideB,
    int Ntrue, int K, int ldc,
    const float* __restrict__ rowscale, const float* __restrict__ colscale,
    const float* __restrict__ bias, void* __restrict__ Cout) {
    __shared__ signed char lds[131072];
    signed char* ldsA = lds;           // 4 units x 16384 B (256 rows x 64 B)
    signed char* ldsB = lds + 65536;   // 4 units x 16384 B

    const int tid = threadIdx.x;
    const int lane = tid & 63, wid = tid >> 6;
    const int wr = wid >> 2, wc = wid & 3;
    const int bm = blockIdx.x, bn = blockIdx.y;
    const long Arow0 = (long)bm * 256;
    const long Bcol0 = (long)bn * 256;

    // Staging: unit = 256 rows x 64 B = 1024 chunks of 16 B; thread handles
    // chunk tid. LDS dest is linear (chunk*16); swizzle folded into the
    // per-lane GLOBAL source chunk.
    const int r0 = tid >> 2;
    const int s0 = (((tid & 3) ^ ((r0 >> 1) & 3)) << 4);
    const signed char* Ag0 = A + (Arow0 + r0) * strideA + s0;
    const signed char* Bg0 = B + (Bcol0 + r0) * strideB + s0;
    const int d0 = tid * 16;

    const int NH = K >> 6;  // number of 64-byte K-halves (phases)

#define STAGE_AB(h)                                 \
    {                                               \
        const int hc_ = (h) < NH ? (h) : NH - 1;    \
        const long ko_ = (long)hc_ << 6;            \
        const int sl_ = ((h) & 3) << 14;            \
        gload16(Ag0 + ko_, ldsA + sl_ + d0);        \
        gload16(Bg0 + ko_, ldsB + sl_ + d0);        \
    }

    // Fragment read offsets: lane reads 16 B at (row, k-chunk q) -> LDS chunk
    // q ^ ((row>>1)&3); per-lane constant swz. Frag i lives at +i*1024.
    const int r = lane & 15, q = lane >> 4;
    const int swz = ((q ^ ((r >> 1) & 3)) << 4);
    const int aoff = (wr * 64 + r) * 64 + swz;  // + i*1024, i = 0..3
    const int boff = (wc * 64 + r) * 64 + swz;  // + n*1024, n = 0..3

    v4i acc[4][4] = {};
    v4i af[4], bf[4];

    // Prologue: stage halves 0,1,2 (6 loads); gate to 4 -> half 0 resident,
    // halves 1,2 in flight.
    STAGE_AB(0); STAGE_AB(1); STAGE_AB(2);
    asm volatile("s_waitcnt vmcnt(4)");
    __builtin_amdgcn_s_barrier();

    for (int h = 0; h < NH; ++h) {
        const signed char* sA = ldsA + ((h & 3) << 14);
        const signed char* sB = ldsB + ((h & 3) << 14);
#pragma unroll
        for (int i = 0; i < 4; ++i) af[i] = *(const v4i*)(sA + aoff + i * 1024);
#pragma unroll
        for (int n = 0; n < 4; ++n) bf[n] = *(const v4i*)(sB + boff + n * 1024);
        // stage half h+3 into slot (h+3)&3 = (h-1)&3 (readers done before the
        // end-of-(h-1) barrier the stager has crossed).
        STAGE_AB(h + 3);
        __builtin_amdgcn_s_setprio(1);
#pragma unroll
        for (int m = 0; m < 4; ++m)
#pragma unroll
            for (int n = 0; n < 4; ++n)
                acc[m][n] = __builtin_amdgcn_mfma_i32_16x16x64_i8(
                    af[m], bf[n], acc[m][n], 0, 0, 0);
        __builtin_amdgcn_s_setprio(0);
        // counted gate: retire half h+1's pair; leave h+2,h+3 (4) in flight.
        asm volatile("s_waitcnt vmcnt(4)");
        __builtin_amdgcn_s_barrier();
    }

    // Epilogue: C/D layout col = lane&15, row = (lane>>4)*4 + reg.
    const int row0 = bm * 256 + wr * 64;
    const int col0 = bn * 256 + wc * 64;
    const int r4 = (lane >> 4) << 2, cl = lane & 15;
#pragma unroll
    for (int m = 0; m < 4; ++m) {
        const int rowb = row0 + m * 16 + r4;
        float rs[4];
#pragma unroll
        for (int rr = 0; rr < 4; ++rr) rs[rr] = rowscale[rowb + rr];
#pragma unroll
        for (int n = 0; n < 4; ++n) {
            const int col = col0 + n * 16 + cl;
            if (col < Ntrue) {
                const float cs = colscale[col];
                const float bs = bias[col];
#pragma unroll
                for (int rr = 0; rr < 4; ++rr) {
                    float v = (float)acc[m][n][rr];
                    v = __fmul_rn(v, rs[rr]);
                    v = __fmul_rn(v, cs);
                    v = __fadd_rn(v, bs);
                    _Float16 hh = (_Float16)v;  // reference rounds to fp16
                    const size_t idx = (size_t)(rowb + rr) * ldc + col;
                    if (EPI == 0) ((_Float16*)Cout)[idx] = hh;
                    else ((float*)Cout)[idx] = (float)hh;
                }
            }
        }
    }
#undef STAGE_AB
}

// -------- exact GELU + per-token dynamic int8 requant (in-place act_q) -------
__global__ __launch_bounds__(256) void gelu_quant(_Float16* __restrict__ fc1,
                                                  float* __restrict__ nscale) {
    __shared__ float gbuf[I_DIM];
    __shared__ float wmax[4];
    const int tid = threadIdx.x, lane = tid & 63, wid = tid >> 6;
    const long t = blockIdx.x;
    const h8* row = (const h8*)(fc1 + t * I_DIM);
    float lmax = 0.f;
    for (int c = tid; c < I_DIM / 8; c += 256) {
        h8 v = row[c];
#pragma unroll
        for (int j = 0; j < 8; ++j) {
            float x = (float)v[j];
            float e = erff(__fdiv_rn(x, 1.41421356237309504880f));
            float g = __fmul_rn(__fmul_rn(0.5f, x), __fadd_rn(1.0f, e));
            gbuf[c * 8 + j] = g;
            lmax = fmaxf(lmax, fabsf(g));
        }
    }
#pragma unroll
    for (int off = 32; off; off >>= 1) lmax = fmaxf(lmax, __shfl_xor(lmax, off, 64));
    if (lane == 0) wmax[wid] = lmax;
    __syncthreads();
    const float gmax = fmaxf(fmaxf(wmax[0], wmax[1]), fmaxf(wmax[2], wmax[3]));
    const float ns = gmax / 127.0f;
    if (tid == 0) nscale[t] = ns;
    unsigned long long* out = (unsigned long long*)(fc1 + t * I_DIM);  // in-place
    for (int c = tid; c < I_DIM / 8; c += 256) {
        unsigned long long pk = 0;
#pragma unroll
        for (int j = 0; j < 8; ++j) {
            float qv = rintf(__fdiv_rn(gbuf[c * 8 + j], ns));
            qv = fminf(fmaxf(qv, -127.f), 127.f);
            pk |= ((unsigned long long)(unsigned char)(signed char)(int)qv) << (8 * j);
        }
        out[c] = pk;
    }
}

extern "C" void kernel_launch(void* const* d_in, const int* in_sizes, int n_in,
                              void* d_out, int out_size, void* d_ws, size_t ws_size,
                              hipStream_t stream) {
    const int* hs = (const int*)d_in[0];        // [B,S,H] int8-in-int32
    const float* scale = (const float*)d_in[1]; // [T]
    const int* w1 = (const int*)d_in[2];        // [I,H]
    const float* w1s = (const float*)d_in[3];   // [I]
    const float* b1 = (const float*)d_in[4];    // [I]
    const int* w2 = (const int*)d_in[5];        // [H,I]
    const float* w2s = (const float*)d_in[6];   // [H]
    const float* b2 = (const float*)d_in[7];    // [H]

    char* ws = (char*)d_ws;
    signed char* xq = (signed char*)ws;                     // 26,214,400 B
    signed char* w1q = xq + (size_t)T_DIM * H_DIM;          // 40,960,000 B
    signed char* w2q = w1q + (size_t)I_DIM * H_DIM;         // 40,960,000 B
    _Float16* fc1h = (_Float16*)(w2q + (size_t)H_DIM * I_DIM);  // chunkT*I fp16
    const size_t fixed = (size_t)T_DIM * H_DIM + 2 * (size_t)I_DIM * H_DIM;

    // choose smallest chunk count whose workspace fits ws_size (deterministic)
    int nc = 1;
    while (nc < 16) {
        size_t need = fixed + ((size_t)T_DIM / nc) * I_DIM * 2 +
                      ((size_t)T_DIM / nc) * 4 + 256;
        if (need <= ws_size) break;
        nc <<= 1;
    }
    const int chunkT = T_DIM / nc;
    float* nscale = (float*)((char*)fc1h + (size_t)chunkT * I_DIM * 2);

    repack_kernel<<<2048, 256, 0, stream>>>(hs, (unsigned int*)xq, (long)T_DIM * H_DIM / 4);
    repack_kernel<<<2048, 256, 0, stream>>>(w1, (unsigned int*)w1q, (long)I_DIM * H_DIM / 4);
    repack_kernel<<<2048, 256, 0, stream>>>(w2, (unsigned int*)w2q, (long)H_DIM * I_DIM / 4);

    const int n2tiles = (H_DIM + 255) / 256;  // 13; last tile col-guarded
    for (int c = 0; c < nc; ++c) {
        const int t0 = c * chunkT;
        gemm_i8_16w<0><<<dim3(chunkT / 256, I_DIM / 256), 1024, 0, stream>>>(
            xq + (size_t)t0 * H_DIM, (long)H_DIM, w1q, (long)H_DIM,
            I_DIM, H_DIM, I_DIM,
            scale + t0, w1s, b1, (void*)fc1h);
        gelu_quant<<<chunkT, 256, 0, stream>>>(fc1h, nscale);
        gemm_i8_16w<1><<<dim3(chunkT / 256, n2tiles), 1024, 0, stream>>>(
            (const signed char*)fc1h, (long)I_DIM * 2, w2q, (long)I_DIM,
            H_DIM, I_DIM, H_DIM,
            nscale, w2s, b2,
            (void*)((float*)d_out + (size_t)t0 * H_DIM));
    }
}